// Round 7
// baseline (360.680 us; speedup 1.0000x reference)
//
#include <hip/hip_runtime.h>

// LocalFeatureAggregation — bf16-MFMA pipeline, point-major activations.
// B=2, N=16384, K=16, D_IN=128, D_OUT=256, GROUPS=16.
//
// Round-7 changes:
//  - lse_m rewritten: one wave per 16-pt tile, ZERO LDS, ZERO barriers.
//    B-fragments built in-register (col = ni*16+l15 -> (k=ni, pt=l15):
//    quad0 = geo ch 0-7, quad1 = ch 8-9 + zeros, quads 2-3 = zeros).
//    Gather uses the lane's own register-resident idx row.
//  - XCD-aware swizzle: batch = (blockIdx&7)>>2 so each batch's 4MB xprev
//    stays resident in its 4 XCDs' L2.
//  - pool_param_kernel precomputes pool1-GN scale/shift for the gather fold.

constexpr int Bc = 2;
constexpr int Nc = 16384;
constexpr int Kc = 16;
constexpr float EPSc = 1e-6f;

typedef __attribute__((ext_vector_type(8))) short short8;
typedef __attribute__((ext_vector_type(4))) short short4v;
typedef __attribute__((ext_vector_type(4))) float floatx4;
typedef __attribute__((ext_vector_type(4))) int intx4;

__device__ inline short f2bf(float x) {
    union { float f; unsigned u; } v; v.f = x;
    unsigned r = v.u + 0x7fffu + ((v.u >> 16) & 1u);
    return (short)(r >> 16);
}
__device__ inline float bf2f(short s) {
    union { unsigned u; float f; } v;
    v.u = ((unsigned)(unsigned short)s) << 16;
    return v.f;
}

// ---- workspace layout ----
// f32 ST[2048]: ST_SC=0, ST_P1=64, ST_P2=128, ST_GEO=256 (B x 65),
//   ST_LP=512 ([stage][b][{psc,psh}x128], 1024), XSC=1536 (2x128), XSH=1792.
constexpr size_t OW_P1W = 0;                        // 128*256
constexpr size_t OW_P2W = OW_P1W + 128*256;         // 256*256
constexpr size_t OW_M2W = OW_P2W + 256*256;         // 512*256
constexpr size_t OW_SCW = OW_M2W + 512*256;         // 512*128 (sc rows 0..511)
constexpr size_t OW_W1  = OW_SCW + 512*128;         // 128*128 (rows 512..639)
constexpr size_t OW_L1W = OW_W1  + 128*128;         // 128*32 (K padded)
constexpr size_t OW_L2W = OW_L1W + 128*32;          // 128*32
constexpr size_t OW_FB  = OW_L2W + 128*32;          // B*N*128
constexpr size_t OW_X1  = OW_FB  + (size_t)Bc*Nc*128;
constexpr size_t OW_M   = OW_X1  + (size_t)Bc*Nc*128;
constexpr size_t OW_Z1  = OW_M   + (size_t)Bc*Nc*256;
constexpr size_t OW_Z2  = OW_Z1  + (size_t)Bc*Nc*128;
constexpr size_t OW_S   = OW_Z2  + (size_t)Bc*Nc*256;

// prep_kernel segment bounds (elements)
constexpr int CV0 = 128*256;            // pool1_w
constexpr int CV1 = CV0 + 256*256;      // pool2_w
constexpr int CV2 = CV1 + 512*256;      // mlp2_w
constexpr int CV3 = CV2 + 512*128;      // sc_w
constexpr int CV4 = CV3 + 128*128;      // w1
constexpr int CV5 = CV4 + 128*32;       // lse1_w padded
constexpr int CV6 = CV5 + 128*32;       // lse2_w padded
constexpr int CVTOT = CV6 + 512;        // + zero ST[0..511]

__global__ void prep_kernel(const float* __restrict__ p1w,
                            const float* __restrict__ p2w,
                            const float* __restrict__ m2w,
                            const float* __restrict__ scw,
                            const float* __restrict__ w1,
                            const float* __restrict__ l1w,
                            const float* __restrict__ l2w,
                            short* __restrict__ W16,
                            float* __restrict__ ST)
{
    int i = blockIdx.x * 256 + threadIdx.x;
    if (i < CV0) { W16[OW_P1W + i] = f2bf(p1w[i]); return; }
    if (i < CV1) { int k = i - CV0; W16[OW_P2W + k] = f2bf(p2w[k]); return; }
    if (i < CV2) { int k = i - CV1; W16[OW_M2W + k] = f2bf(m2w[k]); return; }
    if (i < CV3) { int k = i - CV2; W16[OW_SCW + k] = f2bf(scw[k]); return; }
    if (i < CV4) { int k = i - CV3; W16[OW_W1  + k] = f2bf(w1[k]); return; }
    if (i < CV5) { int k = i - CV4; int o = k >> 5, c = k & 31;
                   W16[OW_L1W + k] = (c < 10) ? f2bf(l1w[o*10+c]) : (short)0; return; }
    if (i < CV6) { int k = i - CV5; int o = k >> 5, c = k & 31;
                   W16[OW_L2W + k] = (c < 10) ? f2bf(l2w[o*10+c]) : (short)0; return; }
    { int k = i - CV6; if (k < 512) ST[k] = 0.f; }
}

// features f32 [b][128][N] -> FB bf16 [b][N][128]
__global__ void feat_t_kernel(const float* __restrict__ in, short* __restrict__ out) {
    int tid  = threadIdx.x;
    int lane = tid & 63, wave = tid >> 6;
    int bb = blockIdx.x / (Nc / 64);
    int n  = (blockIdx.x % (Nc / 64)) * 64 + lane;
    #pragma unroll
    for (int cc = 0; cc < 4; cc++) {
        int c0 = (wave + cc * 4) * 8;
        short8 sv;
        #pragma unroll
        for (int i = 0; i < 8; i++)
            sv[i] = f2bf(in[((size_t)bb * 128 + c0 + i) * Nc + n]);
        *(short8*)&out[((size_t)(bb * Nc + n)) * 128 + c0] = sv;
    }
}

// Reduce S (10) and Q upper-tri (55) of geo over all (n,k), per batch.
__launch_bounds__(256)
__global__ void geo_reduce_kernel(const float* __restrict__ coords,
                                  const int* __restrict__ knn_idx,
                                  const float* __restrict__ knn_dist,
                                  float* __restrict__ dst)   // [B][65]
{
    __shared__ float part[4][65];
    const int tid  = threadIdx.x;
    const int b    = blockIdx.y;
    const int base = blockIdx.x * 256 + tid;          // gridDim.x = 256
    const float* cb  = coords   + (size_t)b * Nc * 3;
    const int*   ib  = knn_idx  + (size_t)b * Nc * Kc;
    const float* db  = knn_dist + (size_t)b * Nc * Kc;

    float acc[65];
    #pragma unroll
    for (int i = 0; i < 65; i++) acc[i] = 0.f;

    #pragma unroll
    for (int it = 0; it < 4; it++) {
        int r = base + it * 65536;                    // covers Nc*Kc = 262144
        int n = r >> 4;
        float cx = cb[n*3+0], cy = cb[n*3+1], cz = cb[n*3+2];
        int   j  = ib[r];
        float nx = cb[j*3+0], ny = cb[j*3+1], nz = cb[j*3+2];
        float d  = db[r];
        float g[10] = {cx,cy,cz,nx,ny,nz,cx-nx,cy-ny,cz-nz,d};
        #pragma unroll
        for (int c = 0; c < 10; c++) acc[c] += g[c];
        int idx = 10;
        #pragma unroll
        for (int c = 0; c < 10; c++)
            #pragma unroll
            for (int c2 = c; c2 < 10; c2++) acc[idx++] += g[c] * g[c2];
    }
    #pragma unroll
    for (int i = 0; i < 65; i++) {
        float v = acc[i];
        #pragma unroll
        for (int off = 1; off < 64; off <<= 1) v += __shfl_xor(v, off);
        acc[i] = v;
    }
    int lane = tid & 63, wave = tid >> 6;
    if (lane == 0) {
        #pragma unroll
        for (int i = 0; i < 65; i++) part[wave][i] = acc[i];
    }
    __syncthreads();
    if (tid < 65) {
        float s = part[0][tid] + part[1][tid] + part[2][tid] + part[3][tid];
        atomicAdd(&dst[b * 65 + tid], s);
    }
}

// Closed-form geo-GN params -> pscale/pshift per (stage,b,o). One block.
__launch_bounds__(512)
__global__ void lse_param_kernel(const float* __restrict__ geoS,  // [B][65]
                                 const float* __restrict__ l1w,
                                 const float* __restrict__ l1b,
                                 const float* __restrict__ l1gw,
                                 const float* __restrict__ l1gb,
                                 const float* __restrict__ l2w,
                                 const float* __restrict__ l2b,
                                 const float* __restrict__ l2gw,
                                 const float* __restrict__ l2gb,
                                 float* __restrict__ lp)          // ST+512
{
    __shared__ float osum[512], osq[512];
    const int tid = threadIdx.x;
    const int s = tid >> 8, r = tid & 255, b = r >> 7, o = r & 127;
    const float* wf = s ? l2w : l1w;
    const float* bf = s ? l2b : l1b;
    const float* gwf = s ? l2gw : l1gw;
    const float* gbf = s ? l2gb : l1gb;
    const float NK = (float)(Nc * Kc);
    const float* S = geoS + b * 65;

    float w[10];
    #pragma unroll
    for (int c = 0; c < 10; c++) w[c] = wf[o * 10 + c];
    float wS = 0.f;
    #pragma unroll
    for (int c = 0; c < 10; c++) wS += w[c] * S[c];
    float q = 0.f;
    {
        int idx = 10;
        #pragma unroll
        for (int c = 0; c < 10; c++)
            #pragma unroll
            for (int c2 = c; c2 < 10; c2++) {
                float t = w[c] * w[c2] * S[idx++];
                q += (c == c2) ? t : 2.f * t;
            }
    }
    float bo = bf[o];
    osum[tid] = NK * bo + wS;
    osq[tid]  = NK * bo * bo + 2.f * bo * wS + q;
    __syncthreads();
    int gb0 = tid & ~7;
    float gs = 0.f, gq = 0.f;
    #pragma unroll
    for (int i = 0; i < 8; i++) { gs += osum[gb0 + i]; gq += osq[gb0 + i]; }
    float cnt  = 8.f * NK;
    float mean = gs / cnt;
    float var  = gq / cnt - mean * mean;
    float iv   = rsqrtf(var + EPSc);
    float psc  = iv * gwf[o];
    float psh  = (bo - mean) * psc + gbf[o];
    lp[s * 512 + b * 256 + o]       = psc;
    lp[s * 512 + b * 256 + 128 + o] = psh;
}

// pool1-GN scale/shift precompute: [b][128] each. One block, 256 threads.
__global__ void pool_param_kernel(const float* __restrict__ st,
                                  const float* __restrict__ gw,
                                  const float* __restrict__ gb,
                                  float cnt,
                                  float* __restrict__ osc,   // [2][128]
                                  float* __restrict__ osh)
{
    int tid = threadIdx.x;
    int b = tid >> 7, c = tid & 127;
    int g = c >> 3;                       // 8 ch/group
    float s0 = st[(b * 16 + g) * 2 + 0];
    float s1 = st[(b * 16 + g) * 2 + 1];
    float mean = s0 / cnt;
    float var  = s1 / cnt - mean * mean;
    float inv  = rsqrtf(var + EPSc);
    float sc = inv * gw[c];
    osc[b * 128 + c] = sc;
    osh[b * 128 + c] = gb[c] - mean * sc;
}

// GEMM: out[b][n][o] = sum_c W[o][c] * X[b][n][c] + bias[o]   (point-major)
// MODE 1: leaky 0.2 -> bf16.  MODE 2: raw bf16 + group stats atomics.
// MODE 3: final — B normalized in staging (pool2 GN+relu), epilogue
//         v + GN(sbuf) -> leaky 0.01 -> f32 [b][o][n].
// MODE 4: merged sc(512, raw+stats)/mlp1(128, leaky0.2) by mo tile.
template<int CIN, int COUT, int GROUP_CH, int MODE>
__launch_bounds__(256)
__global__ void gemm_conv(const short* __restrict__ wA,   // [COUT][CIN] bf16
                          const short* __restrict__ xB,   // [b][N][CIN] bf16
                          const float* __restrict__ bias,
                          short* __restrict__ outb,
                          float* __restrict__ outf,
                          float* __restrict__ stats,
                          const short* __restrict__ sbuf, // [b][N][512] bf16
                          const float* __restrict__ st_sc,
                          const float* __restrict__ gw,
                          const float* __restrict__ gb,
                          float sc_cnt,
                          const float* __restrict__ bst,  // MODE 3: pool2 stats
                          const float* __restrict__ bgw,
                          const float* __restrict__ bgb,
                          float bcnt,
                          const float* __restrict__ bias2, // MODE 4: mlp1 bias
                          short* __restrict__ outb2)       // MODE 4: X1 out
{
    __shared__ short Abuf[128 * 40];
    __shared__ short Bbuf[128 * 40];
    __shared__ float sstat[32];
    __shared__ float smean[4], sinv[4];
    __shared__ float bsc[256], bsh[256];

    const int tid  = threadIdx.x;
    const int n0   = blockIdx.x * 128;
    const int mo   = blockIdx.y * 128;
    const int b    = blockIdx.z;
    const int lane = tid & 63;
    const int wave = tid >> 6;
    const int wm   = (wave >> 1) * 64;
    const int wn   = (wave & 1) * 64;
    const int l15  = lane & 15;
    const int quad = lane >> 4;
    const bool sc_tile = (MODE == 4) && (mo < 512);

    if constexpr (MODE == 2 || MODE == 4) { if (tid < 32) sstat[tid] = 0.f; }
    if constexpr (MODE == 3) {
        if (tid < 4) {
            int g = (mo >> 5) + tid;
            float s0 = st_sc[(b * 16 + g) * 2 + 0];
            float s1 = st_sc[(b * 16 + g) * 2 + 1];
            float mean = s0 / sc_cnt;
            float var  = s1 / sc_cnt - mean * mean;
            smean[tid] = mean;
            sinv[tid]  = rsqrtf(var + EPSc);
        }
        if (tid < CIN) {   // pool2 GN: 256 ch, 16 ch/group
            int g = tid >> 4;
            float s0 = bst[(b * 16 + g) * 2 + 0];
            float s1 = bst[(b * 16 + g) * 2 + 1];
            float mean = s0 / bcnt;
            float var  = s1 / bcnt - mean * mean;
            float inv  = rsqrtf(var + EPSc);
            float sc_  = inv * bgw[tid];
            bsc[tid] = sc_;
            bsh[tid] = bgb[tid] - mean * sc_;
        }
    }

    floatx4 acc[4][4];
    #pragma unroll
    for (int mi = 0; mi < 4; mi++)
        #pragma unroll
        for (int ni = 0; ni < 4; ni++)
            acc[mi][ni] = (floatx4){0.f, 0.f, 0.f, 0.f};

    const short* wAr = wA + (size_t)mo * CIN;
    const short* xBr = xB + (size_t)b * Nc * CIN + (size_t)n0 * CIN;

    for (int c0 = 0; c0 < CIN; c0 += 32) {
        __syncthreads();
        #pragma unroll
        for (int s = 0; s < 2; s++) {
            int e = tid + s * 256;
            int r = e >> 2, q = e & 3;
            *(short8*)&Abuf[r * 40 + q * 8] =
                *(const short8*)(wAr + (size_t)r * CIN + c0 + q * 8);
            short8 v = *(const short8*)(xBr + (size_t)r * CIN + c0 + q * 8);
            if constexpr (MODE == 3) {
                #pragma unroll
                for (int i = 0; i < 8; i++) {
                    int ch = c0 + q * 8 + i;
                    float t = bf2f(v[i]) * bsc[ch] + bsh[ch];
                    v[i] = f2bf(t > 0.f ? t : 0.f);
                }
            }
            *(short8*)&Bbuf[r * 40 + q * 8] = v;
        }
        __syncthreads();

        short8 af[4], bfr[4];
        #pragma unroll
        for (int mi = 0; mi < 4; mi++)
            af[mi] = *(short8*)&Abuf[(wm + mi * 16 + l15) * 40 + quad * 8];
        #pragma unroll
        for (int ni = 0; ni < 4; ni++)
            bfr[ni] = *(short8*)&Bbuf[(wn + ni * 16 + l15) * 40 + quad * 8];
        #pragma unroll
        for (int mi = 0; mi < 4; mi++)
            #pragma unroll
            for (int ni = 0; ni < 4; ni++)
                acc[mi][ni] = __builtin_amdgcn_mfma_f32_16x16x32_bf16(
                    af[mi], bfr[ni], acc[mi][ni], 0, 0, 0);
    }

    // D row(o) = mo+wm+mi*16+quad*4+r, col(n) = n0+wn+ni*16+l15
    #pragma unroll
    for (int mi = 0; mi < 4; mi++) {
        int rowl = wm + mi * 16 + quad * 4;
        float b4[4], gw4[4], gb4[4];
        #pragma unroll
        for (int r = 0; r < 4; r++) {
            if constexpr (MODE == 4) {
                b4[r] = sc_tile ? bias[mo + rowl + r] : bias2[mo - 512 + rowl + r];
            } else {
                b4[r] = bias[mo + rowl + r];
            }
            if constexpr (MODE == 3) {
                gw4[r] = gw[mo + rowl + r];
                gb4[r] = gb[mo + rowl + r];
            }
        }
        float gs = 0.f, gq = 0.f;
        #pragma unroll
        for (int ni = 0; ni < 4; ni++) {
            int col = n0 + wn + ni * 16 + l15;
            if constexpr (MODE == 3) {
                short4v s4 = *(const short4v*)&sbuf[((size_t)(b * Nc + col)) * 512 + mo + rowl];
                int gl = rowl >> 5;
                #pragma unroll
                for (int r = 0; r < 4; r++) {
                    float v = acc[mi][ni][r] + b4[r];
                    float s = bf2f(s4[r]);
                    float sn = (s - smean[gl]) * sinv[gl] * gw4[r] + gb4[r];
                    float o = v + sn;
                    o = o > 0.f ? o : 0.01f * o;
                    outf[((size_t)b * COUT + mo + rowl + r) * Nc + col] = o;
                }
            } else if constexpr (MODE == 4) {
                short4v sv;
                #pragma unroll
                for (int r = 0; r < 4; r++) {
                    float v = acc[mi][ni][r] + b4[r];
                    if (sc_tile) { gs += v; gq += v * v; }
                    else v = v > 0.f ? v : 0.2f * v;
                    sv[r] = f2bf(v);
                }
                if (sc_tile)
                    *(short4v*)&outb[((size_t)(b * Nc + col)) * 512 + mo + rowl] = sv;
                else
                    *(short4v*)&outb2[((size_t)(b * Nc + col)) * 128 + mo - 512 + rowl] = sv;
            } else {
                short4v sv;
                #pragma unroll
                for (int r = 0; r < 4; r++) {
                    float v = acc[mi][ni][r] + b4[r];
                    if constexpr (MODE == 1) v = v > 0.f ? v : 0.2f * v;
                    if constexpr (MODE == 2) { gs += v; gq += v * v; }
                    sv[r] = f2bf(v);
                }
                *(short4v*)&outb[((size_t)(b * Nc + col)) * COUT + mo + rowl] = sv;
            }
        }
        if ((MODE == 2) || (MODE == 4 && sc_tile)) {
            #pragma unroll
            for (int off = 1; off < 16; off <<= 1) {
                gs += __shfl_xor(gs, off);
                gq += __shfl_xor(gq, off);
            }
            if (l15 == 0) {
                int gl = rowl / GROUP_CH;
                atomicAdd(&sstat[gl * 2 + 0], gs);
                atomicAdd(&sstat[gl * 2 + 1], gq);
            }
        }
    }
    if ((MODE == 2) || (MODE == 4 && sc_tile)) {
        __syncthreads();
        constexpr int NG = 128 / GROUP_CH;
        if (tid < 2 * NG) {
            int g0 = mo / GROUP_CH;
            atomicAdd(&stats[b * 32 + (g0 + (tid >> 1)) * 2 + (tid & 1)], sstat[tid]);
        }
    }
}

// LSE v2: one WAVE per 16-point tile. No LDS, no barriers.
// Lane role: pt = l15 (same for MFMA cols, gather, and output), quad = lane>>4.
// B-fragment for tile ni: geo channels quad*8..+7 of (pt=l15, k=ni):
//   quad0 = {cx,cy,cz,nx,ny,nz,cx-nx,cy-ny}, quad1 = {cz-nz, d, 0..}, q2/3 = 0.
// Geo conv: 2 ni-halves x 8 m-tiles x 8 MFMA (C=0), affine(psc/psh)+relu,
// accumulated over ni -> m[n][0:128]. Gather: lane covers 32 ch (quad*32),
// 2 ch-halves x 16 neighbors -> m[n][128:256], optional pool1-GN fold.
template<bool NORM>
__launch_bounds__(256)
__global__ void lse_m_kernel(const float* __restrict__ coords,
                             const int* __restrict__ knn_idx,
                             const float* __restrict__ knn_dist,
                             const short* __restrict__ xprev,   // [b][N][128] bf16
                             const short* __restrict__ wpad,    // [128][32] bf16
                             const float* __restrict__ lp,      // [b][{psc,psh}x128]
                             const float* __restrict__ xscg,    // [b][128] or null
                             const float* __restrict__ xshg,
                             short* __restrict__ m)             // [b][N][256] bf16
{
    const int tid  = threadIdx.x;
    const int wave = tid >> 6, lane = tid & 63;
    const int l15  = lane & 15, quad = lane >> 4;
    // XCD swizzle (grid = 512): xcd = blockIdx&7; batch = xcd>>2.
    const int xcd  = blockIdx.x & 7;
    const int b    = xcd >> 2;
    const int tile = (blockIdx.x >> 3) * 16 + (xcd & 3) * 4 + wave;
    const int n    = tile * 16 + l15;

    // register-resident idx row (64B contiguous)
    const int* irow = knn_idx + ((size_t)(b * Nc) + n) * Kc;
    int jn[16];
    #pragma unroll
    for (int i = 0; i < 4; i++) {
        intx4 t = *(const intx4*)(irow + i * 4);
        jn[i*4+0] = t.x; jn[i*4+1] = t.y; jn[i*4+2] = t.z; jn[i*4+3] = t.w;
    }
    const float* cb = coords + (size_t)b * Nc * 3;

    floatx4 osum[8];
    #pragma unroll
    for (int mt = 0; mt < 8; mt++) osum[mt] = (floatx4){0.f, 0.f, 0.f, 0.f};

    #pragma unroll
    for (int h = 0; h < 2; h++) {
        // build B-fragments for ni = h*8 .. h*8+7 (quad-divergent construction)
        short8 bfr[8];
        if (quad == 0) {
            float cx = cb[n*3+0], cy = cb[n*3+1], cz = cb[n*3+2];
            #pragma unroll
            for (int i = 0; i < 8; i++) {
                int j = jn[h*8+i];
                float nx = cb[j*3+0], ny = cb[j*3+1], nz = cb[j*3+2];
                short8 t;
                t[0]=f2bf(cx); t[1]=f2bf(cy); t[2]=f2bf(cz);
                t[3]=f2bf(nx); t[4]=f2bf(ny); t[5]=f2bf(nz);
                t[6]=f2bf(cx-nx); t[7]=f2bf(cy-ny);
                bfr[i] = t;
            }
        } else if (quad == 1) {
            float cz = cb[n*3+2];
            const float* drow = knn_dist + ((size_t)(b * Nc) + n) * Kc;
            floatx4 d0 = *(const floatx4*)(drow + h*8);
            floatx4 d1 = *(const floatx4*)(drow + h*8 + 4);
            #pragma unroll
            for (int i = 0; i < 8; i++) {
                int j = jn[h*8+i];
                float nz = cb[j*3+2];
                float dd = (i < 4) ? d0[i & 3] : d1[i & 3];
                short8 t;
                t[0] = f2bf(cz - nz); t[1] = f2bf(dd);
                #pragma unroll
                for (int q = 2; q < 8; q++) t[q] = 0;
                bfr[i] = t;
            }
        } else {
            #pragma unroll
            for (int i = 0; i < 8; i++) {
                short8 t;
                #pragma unroll
                for (int q = 0; q < 8; q++) t[q] = 0;
                bfr[i] = t;
            }
        }
        // 8 m-tiles x 8 independent MFMA, affine+relu, reduce over ni
        #pragma unroll
        for (int mt = 0; mt < 8; mt++) {
            short8 af = *(const short8*)(wpad + (mt * 16 + l15) * 32 + quad * 8);
            floatx4 acc[8];
            #pragma unroll
            for (int i = 0; i < 8; i++)
                acc[i] = __builtin_amdgcn_mfma_f32_16x16x32_bf16(
                    af, bfr[i], (floatx4){0.f,0.f,0.f,0.f}, 0, 0, 0);
            floatx4 psc = *(const floatx4*)&lp[b * 256 + mt * 16 + quad * 4];
            floatx4 psh = *(const floatx4*)&lp[b * 256 + 128 + mt * 16 + quad * 4];
            #pragma unroll
            for (int r = 0; r < 4; r++) {
                float s = 0.f;
                #pragma unroll
                for (int i = 0; i < 8; i++) {
                    float v = acc[i][r] * psc[r] + psh[r];
                    s += v > 0.f ? v : 0.f;
                }
                osum[mt][r] += s;
            }
        }
    }
    // store geo half: o = mt*16 + quad*4 + r, point n (same as loads)
    #pragma unroll
    for (int mt = 0; mt < 8; mt++) {
        short4v sv;
        #pragma unroll
        for (int r = 0; r < 4; r++) sv[r] = f2bf(osum[mt][r] * (1.f / 16.f));
        *(short4v*)&m[((size_t)(b * Nc + n)) * 256 + mt * 16 + quad * 4] = sv;
    }

    // gather: lane covers channels quad*32..+31 in 2 halves of 16
    const short* xb = xprev + ((size_t)(b * Nc)) * 128;
    #pragma unroll
    for (int ch = 0; ch < 2; ch++) {
        int c0 = quad * 32 + ch * 16;
        float sc16[16], sh16[16];
        if (NORM) {
            #pragma unroll
            for (int i = 0; i < 4; i++) {
                floatx4 a = *(const floatx4*)&xscg[b * 128 + c0 + i * 4];
                floatx4 s = *(const floatx4*)&xshg[b * 128 + c0 + i * 4];
                #pragma unroll
                for (int r = 0; r < 4; r++) { sc16[i*4+r] = a[r]; sh16[i*4+r] = s[r]; }
            }
        }
        float ga[16];
        #pragma unroll
        for (int i = 0; i < 16; i++) ga[i] = 0.f;
        #pragma unroll
        for (int k = 0; k < 16; k++) {
            const short* row = xb + (size_t)jn[k] * 128 + c0;
            short8 v0 = *(const short8*)row;
            short8 v1 = *(const short8*)(row + 8);
            #pragma unroll
            for (int i = 0; i < 8; i++) {
                float t0 = bf2f(v0[i]);
                float t1 = bf2f(v1[i]);
                if (NORM) {
                    t0 = t0 * sc16[i] + sh16[i];     t0 = t0 > 0.f ? t0 : 0.f;
                    t1 = t1 * sc16[8+i] + sh16[8+i]; t1 = t1 > 0.f ? t1 : 0.f;
                }
                ga[i] += t0; ga[8+i] += t1;
            }
        }
        short8 s0, s1;
        #pragma unroll
        for (int i = 0; i < 8; i++) {
            s0[i] = f2bf(ga[i] * (1.f / 16.f));
            s1[i] = f2bf(ga[8+i] * (1.f / 16.f));
        }
        short* mp = &m[((size_t)(b * Nc + n)) * 256 + 128 + c0];
        *(short8*)mp = s0;
        *(short8*)(mp + 8) = s1;
    }
}

extern "C" void kernel_launch(void* const* d_in, const int* in_sizes, int n_in,
                              void* d_out, int out_size, void* d_ws, size_t ws_size,
                              hipStream_t stream)
{
    const float* coords   = (const float*)d_in[0];
    const float* features = (const float*)d_in[1];
    const float* knn_dist = (const float*)d_in[2];
    const int*   knn_idx  = (const int*)  d_in[3];
    const float* w1       = (const float*)d_in[4];
    const float* b1       = (const float*)d_in[5];
    const float* lse1_w   = (const float*)d_in[6];
    const float* lse1_b   = (const float*)d_in[7];
    const float* lse1_gw  = (const float*)d_in[8];
    const float* lse1_gb  = (const float*)d_in[9];
    const float* pool1_w  = (const float*)d_in[10];
    const float* pool1_b  = (const float*)d_in[11];
    const float* pool1_gw = (const float*)d_in[12];
    const float* pool1_gb = (const float*)d_in[13];
    const float* lse2_w   = (const float*)d_in[14];
    const float* lse2_b   = (const float*)d_in[15];
    const float* lse2_gw  = (const float*)d_in[16];
    const float* lse2_gb  = (const float*)d_in[17];
    const float* pool2_w  = (const float*)d_in[18];
    const float* pool2_b  = (const float*)d_in[19];
    const float* pool2_gw = (const float*)d_in[20];
    const float* pool2_gb = (const float*)d_in[21];
    const float* mlp2_w   = (const float*)d_in[22];
    const float* mlp2_b   = (const float*)d_in[23];
    const float* sc_w     = (const float*)d_in[24];
    const float* sc_b     = (const float*)d_in[25];
    const float* sc_gw    = (const float*)d_in[26];
    const float* sc_gb    = (const float*)d_in[27];
    (void)in_sizes; (void)n_in; (void)out_size; (void)ws_size;

    float* ST = (float*)d_ws;           // 2048 floats
    float* ST_SC  = ST + 0;
    float* ST_P1  = ST + 64;
    float* ST_P2  = ST + 128;
    float* ST_GEO = ST + 256;           // B x 65
    float* ST_LP  = ST + 512;           // [stage][b][{psc,psh}x128]
    float* ST_XSC = ST + 1536;          // [2][128]
    float* ST_XSH = ST + 1792;          // [2][128]
    short* W16 = (short*)(ST + 2048);
    short* P1Wb = W16 + OW_P1W;
    short* P2Wb = W16 + OW_P2W;
    short* M2Wb = W16 + OW_M2W;
    short* SCWb = W16 + OW_SCW;         // rows 0..511 sc, 512..639 w1
    short* L1Wb = W16 + OW_L1W;
    short* L2Wb = W16 + OW_L2W;
    short* FB   = W16 + OW_FB;
    short* X1B  = W16 + OW_X1;
    short* MB   = W16 + OW_M;
    short* Z1   = W16 + OW_Z1;
    short* Z2   = W16 + OW_Z2;
    short* SB   = W16 + OW_S;
    float* out  = (float*)d_out;

    prep_kernel<<<(CVTOT + 255) / 256, 256, 0, stream>>>(
        pool1_w, pool2_w, mlp2_w, sc_w, w1, lse1_w, lse2_w, W16, ST);
    feat_t_kernel<<<Bc * Nc / 64, 256, 0, stream>>>(features, FB);
    geo_reduce_kernel<<<dim3(256, Bc), 256, 0, stream>>>(
        coords, knn_idx, knn_dist, ST_GEO);
    lse_param_kernel<<<1, 512, 0, stream>>>(
        ST_GEO, lse1_w, lse1_b, lse1_gw, lse1_gb,
        lse2_w, lse2_b, lse2_gw, lse2_gb, ST_LP);

    // merged sc (512, raw bf16 + stats, group=32ch) + mlp1 (128, leaky 0.2)
    gemm_conv<128,640,32,4><<<dim3(Nc/128, 5, Bc), 256, 0, stream>>>(
        SCWb, FB, sc_b, SB, nullptr, ST_SC, nullptr, nullptr, nullptr, nullptr, 0.f,
        nullptr, nullptr, nullptr, 0.f, b1, X1B);
    // lse1 (xprev = X1B, no fold) -> MB
    lse_m_kernel<false><<<512, 256, 0, stream>>>(
        coords, knn_idx, knn_dist, X1B, L1Wb, ST_LP, nullptr, nullptr, MB);
    // pool1: 256 -> 128 + stats (group=8ch), raw Z1
    gemm_conv<256,128,8,2><<<dim3(Nc/128, 1, Bc), 256, 0, stream>>>(
        P1Wb, MB, pool1_b, Z1, nullptr, ST_P1, nullptr, nullptr, nullptr, nullptr, 0.f,
        nullptr, nullptr, nullptr, 0.f, nullptr, nullptr);
    pool_param_kernel<<<1, 256, 0, stream>>>(
        ST_P1, pool1_gw, pool1_gb, (float)(8 * Nc), ST_XSC, ST_XSH);
    // lse2 (xprev = raw Z1, pool1 GN+relu folded into gather) -> MB
    lse_m_kernel<true><<<512, 256, 0, stream>>>(
        coords, knn_idx, knn_dist, Z1, L2Wb, ST_LP + 512, ST_XSC, ST_XSH, MB);
    // pool2: 256 -> 256 + stats (group=16ch), raw Z2
    gemm_conv<256,256,16,2><<<dim3(Nc/128, 2, Bc), 256, 0, stream>>>(
        P2Wb, MB, pool2_b, Z2, nullptr, ST_P2, nullptr, nullptr, nullptr, nullptr, 0.f,
        nullptr, nullptr, nullptr, 0.f, nullptr, nullptr);
    // final: mlp2(GN+relu(Z2) folded into staging) + GN(S) -> leaky 0.01 -> f32
    gemm_conv<256,512,32,3><<<dim3(Nc/128, 4, Bc), 256, 0, stream>>>(
        M2Wb, Z2, mlp2_b, nullptr, out, nullptr, SB, ST_SC, sc_gw, sc_gb,
        (float)(32 * Nc), ST_P2, pool2_gw, pool2_gb, (float)(16 * Nc),
        nullptr, nullptr);
}

// Round 8
// 337.556 us; speedup vs baseline: 1.0685x; 1.0685x over previous
//
#include <hip/hip_runtime.h>

// LocalFeatureAggregation — bf16-MFMA pipeline, point-major activations.
// B=2, N=16384, K=16, D_IN=128, D_OUT=256, GROUPS=16.
//
// Round-8 changes (r7 register-built lse_m REVERTED — VGPR 256 halved
// occupancy and partial-line stores doubled WRITE_SIZE):
//  - lse_m restored to the r6 block version (VGPR 96, proven 48.9 us).
//  - prep + feat_t + geo_reduce merged into one setup_kernel (block-range
//    split). geo writes non-atomic per-block partials; lse_param reduces
//    them (avoids zero/atomic race inside the merged kernel).
//  - pool_param folded back into lse2's block start. Dispatches 11 -> 8.

constexpr int Bc = 2;
constexpr int Nc = 16384;
constexpr int Kc = 16;
constexpr float EPSc = 1e-6f;

typedef __attribute__((ext_vector_type(8))) short short8;
typedef __attribute__((ext_vector_type(4))) short short4v;
typedef __attribute__((ext_vector_type(4))) float floatx4;

__device__ inline short f2bf(float x) {
    union { float f; unsigned u; } v; v.f = x;
    unsigned r = v.u + 0x7fffu + ((v.u >> 16) & 1u);
    return (short)(r >> 16);
}
__device__ inline float bf2f(short s) {
    union { unsigned u; float f; } v;
    v.u = ((unsigned)(unsigned short)s) << 16;
    return v.f;
}

// ---- workspace layout ----
// f32 ST[2048]: ST_SC=0, ST_P1=64, ST_P2=128, ST_LP=512 (stage,b,{psc,psh}x128)
// f32 GEOP[512*65] at ST+2048 (geo per-block partials)
// then bf16 (short) region, offsets in shorts:
constexpr int GEOP_F = 512 * 65;                    // 33280
constexpr size_t OW_P1W = 0;                        // 128*256
constexpr size_t OW_P2W = OW_P1W + 128*256;         // 256*256
constexpr size_t OW_M2W = OW_P2W + 256*256;         // 512*256
constexpr size_t OW_SCW = OW_M2W + 512*256;         // 512*128 (sc rows 0..511)
constexpr size_t OW_W1  = OW_SCW + 512*128;         // 128*128 (rows 512..639)
constexpr size_t OW_L1W = OW_W1  + 128*128;         // 128*32 (K padded)
constexpr size_t OW_L2W = OW_L1W + 128*32;          // 128*32
constexpr size_t OW_FB  = OW_L2W + 128*32;          // B*N*128
constexpr size_t OW_X1  = OW_FB  + (size_t)Bc*Nc*128;
constexpr size_t OW_M   = OW_X1  + (size_t)Bc*Nc*128;
constexpr size_t OW_Z1  = OW_M   + (size_t)Bc*Nc*256;
constexpr size_t OW_Z2  = OW_Z1  + (size_t)Bc*Nc*128;
constexpr size_t OW_S   = OW_Z2  + (size_t)Bc*Nc*256;

// setup_kernel segment bounds
constexpr int CV0 = 128*256;            // pool1_w
constexpr int CV1 = CV0 + 256*256;      // pool2_w
constexpr int CV2 = CV1 + 512*256;      // mlp2_w
constexpr int CV3 = CV2 + 512*128;      // sc_w
constexpr int CV4 = CV3 + 128*128;      // w1
constexpr int CV5 = CV4 + 128*32;       // lse1_w padded
constexpr int CV6 = CV5 + 128*32;       // lse2_w padded
constexpr int CVTOT = CV6 + 512;        // + zero ST[0..511]  = 320000
constexpr int NB_PREP = CVTOT / 256;    // 1250 blocks
constexpr int NB_FT   = Bc * Nc / 64;   // 512 blocks
constexpr int NB_GEO  = 512;            // 2 batches x 256 chunks
constexpr int NB_SETUP = NB_PREP + NB_FT + NB_GEO;   // 2274

// Merged setup: [0,NB_PREP) weight cvt + ST zero; [..+NB_FT) feat transpose;
// [..+NB_GEO) geo S/Q partial reduction (non-atomic, per-block row).
__launch_bounds__(256)
__global__ void setup_kernel(const float* __restrict__ p1w,
                             const float* __restrict__ p2w,
                             const float* __restrict__ m2w,
                             const float* __restrict__ scw,
                             const float* __restrict__ w1,
                             const float* __restrict__ l1w,
                             const float* __restrict__ l2w,
                             const float* __restrict__ features,
                             const float* __restrict__ coords,
                             const int* __restrict__ knn_idx,
                             const float* __restrict__ knn_dist,
                             short* __restrict__ W16,
                             float* __restrict__ ST,
                             float* __restrict__ geoP,   // [512][65]
                             short* __restrict__ FB)
{
    const int bid = blockIdx.x;
    const int tid = threadIdx.x;

    if (bid < NB_PREP) {
        int i = bid * 256 + tid;
        if (i < CV0) { W16[OW_P1W + i] = f2bf(p1w[i]); return; }
        if (i < CV1) { int k = i - CV0; W16[OW_P2W + k] = f2bf(p2w[k]); return; }
        if (i < CV2) { int k = i - CV1; W16[OW_M2W + k] = f2bf(m2w[k]); return; }
        if (i < CV3) { int k = i - CV2; W16[OW_SCW + k] = f2bf(scw[k]); return; }
        if (i < CV4) { int k = i - CV3; W16[OW_W1  + k] = f2bf(w1[k]); return; }
        if (i < CV5) { int k = i - CV4; int o = k >> 5, c = k & 31;
                       W16[OW_L1W + k] = (c < 10) ? f2bf(l1w[o*10+c]) : (short)0; return; }
        if (i < CV6) { int k = i - CV5; int o = k >> 5, c = k & 31;
                       W16[OW_L2W + k] = (c < 10) ? f2bf(l2w[o*10+c]) : (short)0; return; }
        { int k = i - CV6; if (k < 512) ST[k] = 0.f; }
        return;
    }
    if (bid < NB_PREP + NB_FT) {
        int fb = bid - NB_PREP;
        int lane = tid & 63, wave = tid >> 6;
        int bb = fb / 256;
        int n  = (fb % 256) * 64 + lane;
        #pragma unroll
        for (int cc = 0; cc < 4; cc++) {
            int c0 = (wave + cc * 4) * 8;
            short8 sv;
            #pragma unroll
            for (int i = 0; i < 8; i++)
                sv[i] = f2bf(features[((size_t)bb * 128 + c0 + i) * Nc + n]);
            *(short8*)&FB[((size_t)(bb * Nc + n)) * 128 + c0] = sv;
        }
        return;
    }
    // geo segment
    {
        __shared__ float part[4][65];
        int gb = bid - NB_PREP - NB_FT;            // [0,512)
        int b = gb >> 8, chunk = gb & 255;
        int base = chunk * 256 + tid;
        const float* cb  = coords   + (size_t)b * Nc * 3;
        const int*   ib  = knn_idx  + (size_t)b * Nc * Kc;
        const float* db  = knn_dist + (size_t)b * Nc * Kc;

        float acc[65];
        #pragma unroll
        for (int i = 0; i < 65; i++) acc[i] = 0.f;
        #pragma unroll
        for (int it = 0; it < 4; it++) {
            int r = base + it * 65536;             // covers Nc*Kc = 262144
            int n = r >> 4;
            float cx = cb[n*3+0], cy = cb[n*3+1], cz = cb[n*3+2];
            int   j  = ib[r];
            float nx = cb[j*3+0], ny = cb[j*3+1], nz = cb[j*3+2];
            float d  = db[r];
            float g[10] = {cx,cy,cz,nx,ny,nz,cx-nx,cy-ny,cz-nz,d};
            #pragma unroll
            for (int c = 0; c < 10; c++) acc[c] += g[c];
            int idx = 10;
            #pragma unroll
            for (int c = 0; c < 10; c++)
                #pragma unroll
                for (int c2 = c; c2 < 10; c2++) acc[idx++] += g[c] * g[c2];
        }
        #pragma unroll
        for (int i = 0; i < 65; i++) {
            float v = acc[i];
            #pragma unroll
            for (int off = 1; off < 64; off <<= 1) v += __shfl_xor(v, off);
            acc[i] = v;
        }
        int lane = tid & 63, wave = tid >> 6;
        if (lane == 0) {
            #pragma unroll
            for (int i = 0; i < 65; i++) part[wave][i] = acc[i];
        }
        __syncthreads();
        if (tid < 65)
            geoP[gb * 65 + tid] =
                part[0][tid] + part[1][tid] + part[2][tid] + part[3][tid];
    }
}

// Closed-form geo-GN params. Pre-phase reduces geoP partials; main phase:
// pscale/pshift per (stage,b,o). One block, 512 threads.
__launch_bounds__(512)
__global__ void lse_param_kernel(const float* __restrict__ geoP,  // [512][65]
                                 const float* __restrict__ l1w,
                                 const float* __restrict__ l1b,
                                 const float* __restrict__ l1gw,
                                 const float* __restrict__ l1gb,
                                 const float* __restrict__ l2w,
                                 const float* __restrict__ l2b,
                                 const float* __restrict__ l2gw,
                                 const float* __restrict__ l2gb,
                                 float* __restrict__ lp)          // ST+512
{
    __shared__ float S2[130];
    __shared__ float osum[512], osq[512];
    const int tid = threadIdx.x;
    if (tid < 130) {
        int b = tid / 65, i = tid % 65;
        const float* p = geoP + (size_t)b * 256 * 65 + i;
        float s = 0.f;
        #pragma unroll 8
        for (int c = 0; c < 256; c++) s += p[c * 65];
        S2[tid] = s;
    }
    __syncthreads();

    const int s = tid >> 8, r = tid & 255, b = r >> 7, o = r & 127;
    const float* wf = s ? l2w : l1w;
    const float* bf = s ? l2b : l1b;
    const float* gwf = s ? l2gw : l1gw;
    const float* gbf = s ? l2gb : l1gb;
    const float NK = (float)(Nc * Kc);
    const float* S = &S2[b * 65];

    float w[10];
    #pragma unroll
    for (int c = 0; c < 10; c++) w[c] = wf[o * 10 + c];
    float wS = 0.f;
    #pragma unroll
    for (int c = 0; c < 10; c++) wS += w[c] * S[c];
    float q = 0.f;
    {
        int idx = 10;
        #pragma unroll
        for (int c = 0; c < 10; c++)
            #pragma unroll
            for (int c2 = c; c2 < 10; c2++) {
                float t = w[c] * w[c2] * S[idx++];
                q += (c == c2) ? t : 2.f * t;
            }
    }
    float bo = bf[o];
    osum[tid] = NK * bo + wS;
    osq[tid]  = NK * bo * bo + 2.f * bo * wS + q;
    __syncthreads();
    int gb0 = tid & ~7;
    float gs = 0.f, gq = 0.f;
    #pragma unroll
    for (int i = 0; i < 8; i++) { gs += osum[gb0 + i]; gq += osq[gb0 + i]; }
    float cnt  = 8.f * NK;
    float mean = gs / cnt;
    float var  = gq / cnt - mean * mean;
    float iv   = rsqrtf(var + EPSc);
    float psc  = iv * gwf[o];
    float psh  = (bo - mean) * psc + gbf[o];
    lp[s * 512 + b * 256 + o]       = psc;
    lp[s * 512 + b * 256 + 128 + o] = psh;
}

// GEMM: out[b][n][o] = sum_c W[o][c] * X[b][n][c] + bias[o]   (point-major)
// MODE 1: leaky 0.2 -> bf16.  MODE 2: raw bf16 + group stats atomics.
// MODE 3: final — B normalized in staging (pool2 GN+relu), epilogue
//         v + GN(sbuf) -> leaky 0.01 -> f32 [b][o][n].
// MODE 4: merged sc(512, raw+stats)/mlp1(128, leaky0.2) by mo tile.
template<int CIN, int COUT, int GROUP_CH, int MODE>
__launch_bounds__(256)
__global__ void gemm_conv(const short* __restrict__ wA,   // [COUT][CIN] bf16
                          const short* __restrict__ xB,   // [b][N][CIN] bf16
                          const float* __restrict__ bias,
                          short* __restrict__ outb,
                          float* __restrict__ outf,
                          float* __restrict__ stats,
                          const short* __restrict__ sbuf, // [b][N][512] bf16
                          const float* __restrict__ st_sc,
                          const float* __restrict__ gw,
                          const float* __restrict__ gb,
                          float sc_cnt,
                          const float* __restrict__ bst,  // MODE 3: pool2 stats
                          const float* __restrict__ bgw,
                          const float* __restrict__ bgb,
                          float bcnt,
                          const float* __restrict__ bias2, // MODE 4: mlp1 bias
                          short* __restrict__ outb2)       // MODE 4: X1 out
{
    __shared__ short Abuf[128 * 40];
    __shared__ short Bbuf[128 * 40];
    __shared__ float sstat[32];
    __shared__ float smean[4], sinv[4];
    __shared__ float bsc[256], bsh[256];

    const int tid  = threadIdx.x;
    const int n0   = blockIdx.x * 128;
    const int mo   = blockIdx.y * 128;
    const int b    = blockIdx.z;
    const int lane = tid & 63;
    const int wave = tid >> 6;
    const int wm   = (wave >> 1) * 64;
    const int wn   = (wave & 1) * 64;
    const int l15  = lane & 15;
    const int quad = lane >> 4;
    const bool sc_tile = (MODE == 4) && (mo < 512);

    if constexpr (MODE == 2 || MODE == 4) { if (tid < 32) sstat[tid] = 0.f; }
    if constexpr (MODE == 3) {
        if (tid < 4) {
            int g = (mo >> 5) + tid;
            float s0 = st_sc[(b * 16 + g) * 2 + 0];
            float s1 = st_sc[(b * 16 + g) * 2 + 1];
            float mean = s0 / sc_cnt;
            float var  = s1 / sc_cnt - mean * mean;
            smean[tid] = mean;
            sinv[tid]  = rsqrtf(var + EPSc);
        }
        if (tid < CIN) {   // pool2 GN: 256 ch, 16 ch/group
            int g = tid >> 4;
            float s0 = bst[(b * 16 + g) * 2 + 0];
            float s1 = bst[(b * 16 + g) * 2 + 1];
            float mean = s0 / bcnt;
            float var  = s1 / bcnt - mean * mean;
            float inv  = rsqrtf(var + EPSc);
            float sc_  = inv * bgw[tid];
            bsc[tid] = sc_;
            bsh[tid] = bgb[tid] - mean * sc_;
        }
    }

    floatx4 acc[4][4];
    #pragma unroll
    for (int mi = 0; mi < 4; mi++)
        #pragma unroll
        for (int ni = 0; ni < 4; ni++)
            acc[mi][ni] = (floatx4){0.f, 0.f, 0.f, 0.f};

    const short* wAr = wA + (size_t)mo * CIN;
    const short* xBr = xB + (size_t)b * Nc * CIN + (size_t)n0 * CIN;

    for (int c0 = 0; c0 < CIN; c0 += 32) {
        __syncthreads();
        #pragma unroll
        for (int s = 0; s < 2; s++) {
            int e = tid + s * 256;
            int r = e >> 2, q = e & 3;
            *(short8*)&Abuf[r * 40 + q * 8] =
                *(const short8*)(wAr + (size_t)r * CIN + c0 + q * 8);
            short8 v = *(const short8*)(xBr + (size_t)r * CIN + c0 + q * 8);
            if constexpr (MODE == 3) {
                #pragma unroll
                for (int i = 0; i < 8; i++) {
                    int ch = c0 + q * 8 + i;
                    float t = bf2f(v[i]) * bsc[ch] + bsh[ch];
                    v[i] = f2bf(t > 0.f ? t : 0.f);
                }
            }
            *(short8*)&Bbuf[r * 40 + q * 8] = v;
        }
        __syncthreads();

        short8 af[4], bfr[4];
        #pragma unroll
        for (int mi = 0; mi < 4; mi++)
            af[mi] = *(short8*)&Abuf[(wm + mi * 16 + l15) * 40 + quad * 8];
        #pragma unroll
        for (int ni = 0; ni < 4; ni++)
            bfr[ni] = *(short8*)&Bbuf[(wn + ni * 16 + l15) * 40 + quad * 8];
        #pragma unroll
        for (int mi = 0; mi < 4; mi++)
            #pragma unroll
            for (int ni = 0; ni < 4; ni++)
                acc[mi][ni] = __builtin_amdgcn_mfma_f32_16x16x32_bf16(
                    af[mi], bfr[ni], acc[mi][ni], 0, 0, 0);
    }

    // D row(o) = mo+wm+mi*16+quad*4+r, col(n) = n0+wn+ni*16+l15
    #pragma unroll
    for (int mi = 0; mi < 4; mi++) {
        int rowl = wm + mi * 16 + quad * 4;
        float b4[4], gw4[4], gb4[4];
        #pragma unroll
        for (int r = 0; r < 4; r++) {
            if constexpr (MODE == 4) {
                b4[r] = sc_tile ? bias[mo + rowl + r] : bias2[mo - 512 + rowl + r];
            } else {
                b4[r] = bias[mo + rowl + r];
            }
            if constexpr (MODE == 3) {
                gw4[r] = gw[mo + rowl + r];
                gb4[r] = gb[mo + rowl + r];
            }
        }
        float gs = 0.f, gq = 0.f;
        #pragma unroll
        for (int ni = 0; ni < 4; ni++) {
            int col = n0 + wn + ni * 16 + l15;
            if constexpr (MODE == 3) {
                short4v s4 = *(const short4v*)&sbuf[((size_t)(b * Nc + col)) * 512 + mo + rowl];
                int gl = rowl >> 5;
                #pragma unroll
                for (int r = 0; r < 4; r++) {
                    float v = acc[mi][ni][r] + b4[r];
                    float s = bf2f(s4[r]);
                    float sn = (s - smean[gl]) * sinv[gl] * gw4[r] + gb4[r];
                    float o = v + sn;
                    o = o > 0.f ? o : 0.01f * o;
                    outf[((size_t)b * COUT + mo + rowl + r) * Nc + col] = o;
                }
            } else if constexpr (MODE == 4) {
                short4v sv;
                #pragma unroll
                for (int r = 0; r < 4; r++) {
                    float v = acc[mi][ni][r] + b4[r];
                    if (sc_tile) { gs += v; gq += v * v; }
                    else v = v > 0.f ? v : 0.2f * v;
                    sv[r] = f2bf(v);
                }
                if (sc_tile)
                    *(short4v*)&outb[((size_t)(b * Nc + col)) * 512 + mo + rowl] = sv;
                else
                    *(short4v*)&outb2[((size_t)(b * Nc + col)) * 128 + mo - 512 + rowl] = sv;
            } else {
                short4v sv;
                #pragma unroll
                for (int r = 0; r < 4; r++) {
                    float v = acc[mi][ni][r] + b4[r];
                    if constexpr (MODE == 1) v = v > 0.f ? v : 0.2f * v;
                    if constexpr (MODE == 2) { gs += v; gq += v * v; }
                    sv[r] = f2bf(v);
                }
                *(short4v*)&outb[((size_t)(b * Nc + col)) * COUT + mo + rowl] = sv;
            }
        }
        if ((MODE == 2) || (MODE == 4 && sc_tile)) {
            #pragma unroll
            for (int off = 1; off < 16; off <<= 1) {
                gs += __shfl_xor(gs, off);
                gq += __shfl_xor(gq, off);
            }
            if (l15 == 0) {
                int gl = rowl / GROUP_CH;
                atomicAdd(&sstat[gl * 2 + 0], gs);
                atomicAdd(&sstat[gl * 2 + 1], gq);
            }
        }
    }
    if ((MODE == 2) || (MODE == 4 && sc_tile)) {
        __syncthreads();
        constexpr int NG = 128 / GROUP_CH;
        if (tid < 2 * NG) {
            int g0 = mo / GROUP_CH;
            atomicAdd(&stats[b * 32 + (g0 + (tid >> 1)) * 2 + (tid & 1)], sstat[tid]);
        }
    }
}

// LSE (r6 version): per 16-point tile, ONE barrier.
//  - geo conv via MFMA (A-frags from global, GN via precomputed pscale/pshift)
//    + relu + mean_k -> m[n][0:128]
//  - neighbor gather-mean of point-major xprev -> m[n][128:256]
//    (optional folded pool1-GN+relu on xprev)
__launch_bounds__(256)
__global__ void lse_m_kernel(const float* __restrict__ coords,
                             const int* __restrict__ knn_idx,
                             const float* __restrict__ knn_dist,
                             const short* __restrict__ xprev,   // [b][N][128] bf16
                             const short* __restrict__ wpad,    // [128][32] bf16
                             const float* __restrict__ lp,      // [b][{psc,psh}x128]
                             const float* __restrict__ xst,     // pool1 stats or null
                             const float* __restrict__ xgw,
                             const float* __restrict__ xgb,
                             float xcnt,
                             short* __restrict__ m)             // [b][N][256] bf16
{
    __shared__ short Bbuf[256 * 40];
    __shared__ int   jl[256];
    __shared__ float xscs[128], xshs[128];

    const int tid = threadIdx.x;
    const int b   = blockIdx.x >> 10;          // Nc/16 = 1024
    const int n0  = (blockIdx.x & 1023) * 16;
    const bool norm = (xst != nullptr);

    if (norm && tid < 128) {   // pool1 GN fold: 128 ch, 8 ch/group
        int g = tid >> 3;
        float s0 = xst[(b * 16 + g) * 2 + 0];
        float s1 = xst[(b * 16 + g) * 2 + 1];
        float mean = s0 / xcnt;
        float var  = s1 / xcnt - mean * mean;
        float inv  = rsqrtf(var + EPSc);
        float sc_  = inv * xgw[tid];
        xscs[tid] = sc_;
        xshs[tid] = xgb[tid] - mean * sc_;
    }
    // geo features for the 16x16 (pt,k) tile -> Bbuf[col=k*16+pt][c], rows
    // 10..31 zeroed inline (K padded to 32).
    {
        int pt = tid & 15, k = tid >> 4;
        int n  = n0 + pt;
        const float* cb = coords + (size_t)b * Nc * 3;
        float cx = cb[n*3+0], cy = cb[n*3+1], cz = cb[n*3+2];
        int   j  = knn_idx[((size_t)b * Nc + n) * Kc + k];
        float nx = cb[j*3+0], ny = cb[j*3+1], nz = cb[j*3+2];
        float d  = knn_dist[((size_t)b * Nc + n) * Kc + k];
        int col = k * 16 + pt;
        short8 w0, w1, zz;
        w0[0]=f2bf(cx); w0[1]=f2bf(cy); w0[2]=f2bf(cz);
        w0[3]=f2bf(nx); w0[4]=f2bf(ny); w0[5]=f2bf(nz);
        w0[6]=f2bf(cx-nx); w0[7]=f2bf(cy-ny);
        w1[0]=f2bf(cz-nz); w1[1]=f2bf(d);
        #pragma unroll
        for (int i = 2; i < 8; i++) w1[i] = 0;
        #pragma unroll
        for (int i = 0; i < 8; i++) zz[i] = 0;
        *(short8*)&Bbuf[col * 40 + 0]  = w0;
        *(short8*)&Bbuf[col * 40 + 8]  = w1;
        *(short8*)&Bbuf[col * 40 + 16] = zz;
        *(short8*)&Bbuf[col * 40 + 24] = zz;
        jl[col] = j;
    }
    __syncthreads();

    const int lane = tid & 63, wave = tid >> 6;
    const int l15 = lane & 15, quad = lane >> 4;
    // B fragments: tile ni <-> neighbor k, lane col <-> pt
    short8 bfr[16];
    #pragma unroll
    for (int ni = 0; ni < 16; ni++)
        bfr[ni] = *(short8*)&Bbuf[(ni * 16 + l15) * 40 + quad * 8];
    #pragma unroll
    for (int mt2 = 0; mt2 < 2; mt2++) {
        int mt = wave * 2 + mt2;
        short8 af = *(const short8*)(wpad + (mt * 16 + l15) * 32 + quad * 8);
        floatx4 acc[16];
        #pragma unroll
        for (int ni = 0; ni < 16; ni++) {
            acc[ni] = (floatx4){0.f, 0.f, 0.f, 0.f};
            acc[ni] = __builtin_amdgcn_mfma_f32_16x16x32_bf16(af, bfr[ni], acc[ni], 0, 0, 0);
        }
        short4v sv;
        #pragma unroll
        for (int r = 0; r < 4; r++) {
            int o = mt * 16 + quad * 4 + r;
            float psc = lp[b * 256 + o];
            float psh = lp[b * 256 + 128 + o];
            float s = 0.f;
            #pragma unroll
            for (int ni = 0; ni < 16; ni++) {
                float v = acc[ni][r] * psc + psh;
                s += v > 0.f ? v : 0.f;
            }
            sv[r] = f2bf(s * (1.f / 16.f));
        }
        *(short4v*)&m[((size_t)(b * Nc + n0 + l15)) * 256 + mt * 16 + quad * 4] = sv;
    }

    // neighbor gather-mean: thread (cs, tp), 16 x b128 loads
    {
        int tp = tid & 15, cs = tid >> 4;
        float sc8[8], sh8[8];
        if (norm) {
            #pragma unroll
            for (int i = 0; i < 8; i++) { sc8[i] = xscs[cs*8+i]; sh8[i] = xshs[cs*8+i]; }
        }
        float acc8[8];
        #pragma unroll
        for (int i = 0; i < 8; i++) acc8[i] = 0.f;
        #pragma unroll
        for (int k = 0; k < 16; k++) {
            int j = jl[k * 16 + tp];
            short8 v = *(const short8*)&xprev[((size_t)(b * Nc + j)) * 128 + cs * 8];
            if (norm) {
                #pragma unroll
                for (int i = 0; i < 8; i++) {
                    float t = bf2f(v[i]) * sc8[i] + sh8[i];
                    acc8[i] += t > 0.f ? t : 0.f;
                }
            } else {
                #pragma unroll
                for (int i = 0; i < 8; i++) acc8[i] += bf2f(v[i]);
            }
        }
        short8 sv;
        #pragma unroll
        for (int i = 0; i < 8; i++) sv[i] = f2bf(acc8[i] * (1.f / 16.f));
        *(short8*)&m[((size_t)(b * Nc + n0 + tp)) * 256 + 128 + cs * 8] = sv;
    }
}

extern "C" void kernel_launch(void* const* d_in, const int* in_sizes, int n_in,
                              void* d_out, int out_size, void* d_ws, size_t ws_size,
                              hipStream_t stream)
{
    const float* coords   = (const float*)d_in[0];
    const float* features = (const float*)d_in[1];
    const float* knn_dist = (const float*)d_in[2];
    const int*   knn_idx  = (const int*)  d_in[3];
    const float* w1       = (const float*)d_in[4];
    const float* b1       = (const float*)d_in[5];
    const float* lse1_w   = (const float*)d_in[6];
    const float* lse1_b   = (const float*)d_in[7];
    const float* lse1_gw  = (const float*)d_in[8];
    const float* lse1_gb  = (const float*)d_in[9];
    const float* pool1_w  = (const float*)d_in[10];
    const float* pool1_b  = (const float*)d_in[11];
    const float* pool1_gw = (const float*)d_in[12];
    const float* pool1_gb = (const float*)d_in[13];
    const float* lse2_w   = (const float*)d_in[14];
    const float* lse2_b   = (const float*)d_in[15];
    const float* lse2_gw  = (const float*)d_in[16];
    const float* lse2_gb  = (const float*)d_in[17];
    const float* pool2_w  = (const float*)d_in[18];
    const float* pool2_b  = (const float*)d_in[19];
    const float* pool2_gw = (const float*)d_in[20];
    const float* pool2_gb = (const float*)d_in[21];
    const float* mlp2_w   = (const float*)d_in[22];
    const float* mlp2_b   = (const float*)d_in[23];
    const float* sc_w     = (const float*)d_in[24];
    const float* sc_b     = (const float*)d_in[25];
    const float* sc_gw    = (const float*)d_in[26];
    const float* sc_gb    = (const float*)d_in[27];
    (void)in_sizes; (void)n_in; (void)out_size; (void)ws_size;

    float* ST = (float*)d_ws;           // 2048 floats + GEOP
    float* ST_SC  = ST + 0;
    float* ST_P1  = ST + 64;
    float* ST_P2  = ST + 128;
    float* ST_LP  = ST + 512;           // [stage][b][{psc,psh}x128]
    float* GEOP   = ST + 2048;          // [512][65]
    short* W16 = (short*)(ST + 2048 + GEOP_F);
    short* P1Wb = W16 + OW_P1W;
    short* P2Wb = W16 + OW_P2W;
    short* M2Wb = W16 + OW_M2W;
    short* SCWb = W16 + OW_SCW;         // rows 0..511 sc, 512..639 w1
    short* L1Wb = W16 + OW_L1W;
    short* L2Wb = W16 + OW_L2W;
    short* FB   = W16 + OW_FB;
    short* X1B  = W16 + OW_X1;
    short* MB   = W16 + OW_M;
    short* Z1   = W16 + OW_Z1;
    short* Z2   = W16 + OW_Z2;
    short* SB   = W16 + OW_S;
    float* out  = (float*)d_out;

    // merged prep + feature transpose + geo partial reduction
    setup_kernel<<<NB_SETUP, 256, 0, stream>>>(
        pool1_w, pool2_w, mlp2_w, sc_w, w1, lse1_w, lse2_w,
        features, coords, knn_idx, knn_dist, W16, ST, GEOP, FB);
    lse_param_kernel<<<1, 512, 0, stream>>>(
        GEOP, lse1_w, lse1_b, lse1_gw, lse1_gb,
        lse2_w, lse2_b, lse2_gw, lse2_gb, ST_LP);

    // merged sc (512, raw bf16 + stats, group=32ch) + mlp1 (128, leaky 0.2)
    gemm_conv<128,640,32,4><<<dim3(Nc/128, 5, Bc), 256, 0, stream>>>(
        SCWb, FB, sc_b, SB, nullptr, ST_SC, nullptr, nullptr, nullptr, nullptr, 0.f,
        nullptr, nullptr, nullptr, 0.f, b1, X1B);
    // lse1 (xprev = X1B, no fold) -> MB
    lse_m_kernel<<<Bc * Nc / 16, 256, 0, stream>>>(
        coords, knn_idx, knn_dist, X1B, L1Wb, ST_LP,
        nullptr, nullptr, nullptr, 0.f, MB);
    // pool1: 256 -> 128 + stats (group=8ch), raw Z1
    gemm_conv<256,128,8,2><<<dim3(Nc/128, 1, Bc), 256, 0, stream>>>(
        P1Wb, MB, pool1_b, Z1, nullptr, ST_P1, nullptr, nullptr, nullptr, nullptr, 0.f,
        nullptr, nullptr, nullptr, 0.f, nullptr, nullptr);
    // lse2 (xprev = raw Z1, pool1 GN+relu folded into gather) -> MB
    lse_m_kernel<<<Bc * Nc / 16, 256, 0, stream>>>(
        coords, knn_idx, knn_dist, Z1, L2Wb, ST_LP + 512,
        ST_P1, pool1_gw, pool1_gb, (float)(8 * Nc), MB);
    // pool2: 256 -> 256 + stats (group=16ch), raw Z2
    gemm_conv<256,256,16,2><<<dim3(Nc/128, 2, Bc), 256, 0, stream>>>(
        P2Wb, MB, pool2_b, Z2, nullptr, ST_P2, nullptr, nullptr, nullptr, nullptr, 0.f,
        nullptr, nullptr, nullptr, 0.f, nullptr, nullptr);
    // final: mlp2(GN+relu(Z2) folded into staging) + GN(S) -> leaky 0.01 -> f32
    gemm_conv<256,512,32,3><<<dim3(Nc/128, 4, Bc), 256, 0, stream>>>(
        M2Wb, Z2, mlp2_b, nullptr, out, nullptr, SB, ST_SC, sc_gw, sc_gb,
        (float)(32 * Nc), ST_P2, pool2_gw, pool2_gb, (float)(16 * Nc),
        nullptr, nullptr);
}